// Round 5
// baseline (1506.492 us; speedup 1.0000x reference)
//
#include <hip/hip_runtime.h>
#include <hip/hip_bf16.h>
#include <math.h>

typedef __hip_bfloat16 bf16;
__device__ __forceinline__ float toF(float v){ return v; }
__device__ __forceinline__ float toF(bf16 v){ return __bfloat162float(v); }
__device__ __forceinline__ bf16 f2bf(float v){ return __float2bfloat16(v); }

#define D_    300
#define H_    5
#define NB    64
#define LL    1024
#define KK    64
#define ETXT  2048
#define EIMG  512
#define MAXDEG 128
#define KP2   1536   // agg row width: H*D=1500 padded to 48*32
#define NT    19     // n-tiles of 16 covering 300 output cols (304)

typedef __attribute__((ext_vector_type(8))) short short8;
typedef __attribute__((ext_vector_type(4))) float f32x4;

// Mask storage modes: 0 = 4-byte word, 1 = 2-byte, 2 = 1-byte (bool), 3 = 8-byte.
__device__ __forceinline__ int read_mask(const void* p, int i, int mode) {
  switch (mode) {
    case 1: return ((const unsigned short*)p)[i] != 0;
    case 2: return ((const unsigned char*)p)[i] != 0;
    case 3: { const unsigned int* w = (const unsigned int*)p;
              return (w[2*i] | w[2*i+1]) != 0; }
    default: return ((const unsigned int*)p)[i] != 0;
  }
}

__global__ void k_detect(const unsigned int* __restrict__ w, int nwords,
                         int* __restrict__ mode) {
  __shared__ unsigned int se[256], so[256];
  unsigned int oe = 0, oo = 0;
  for (int i = threadIdx.x; i < nwords; i += 256) {
    unsigned int v = w[i];
    if (i & 1) oo |= v; else oe |= v;
  }
  se[threadIdx.x] = oe; so[threadIdx.x] = oo;
  __syncthreads();
  for (int s = 128; s; s >>= 1) {
    if (threadIdx.x < s) { se[threadIdx.x] |= se[threadIdx.x+s]; so[threadIdx.x] |= so[threadIdx.x+s]; }
    __syncthreads();
  }
  if (threadIdx.x == 0) {
    unsigned int O = se[0] | so[0];
    int m = 0;
    if (O == 0u) m = 0;
    else if ((O & 0xFFFFu) == 0x3F80u) m = 1;
    else if ((O >> 16) == 0x3F80u && (O & 0xFFFFu) == 0u) m = 0;
    else if ((O >> 16) == 0x3FF0u) m = 3;
    else if (O <= 1u) m = (so[0] == 0u && se[0] != 0u) ? 3 : 0;
    else if ((O & 0xFEFEFEFEu) == 0u) m = 2;
    mode[0] = m;
  }
}

// ---------------- c[n,d] = sum_l score[n,l,d]*t2[n,l,d] ----------------
__global__ void k_c(const float* __restrict__ t2, const float* __restrict__ score,
                    float* __restrict__ c) {
  int n = blockIdx.x;
  int d = blockIdx.y * 128 + threadIdx.x;
  if (d >= D_) return;
  const float* tp = t2 + (size_t)n * LL * D_ + d;
  const float* sp = score + (size_t)n * LL * D_ + d;
  float acc = 0.f;
  for (int l = 0; l < LL; ++l)
    acc += tp[(size_t)l * D_] * sp[(size_t)l * D_];
  c[n * D_ + d] = acc;
}

__device__ __forceinline__ float clamp_logit(float v) {
  if (!(v > -1e30f)) v = -1e30f;
  if (v > 1e30f) v = 1e30f;
  return v;
}

// ---------------- pa_token logits (wave per row) ----------------
__global__ void k_logits_tok(const float* __restrict__ x, const float* __restrict__ w,
                             const float* __restrict__ b, const void* __restrict__ mask,
                             const int* __restrict__ mmode,
                             float* __restrict__ logits, int rows) {
  int row = blockIdx.x * blockDim.y + threadIdx.y;
  if (row >= rows) return;
  int lane = threadIdx.x;
  const float* xp = x + (size_t)row * D_;
  float acc = 0.f;
  for (int d = lane; d < D_; d += 64) acc += xp[d] * w[d];
#pragma unroll
  for (int off = 32; off; off >>= 1) acc += __shfl_down(acc, off);
  if (lane == 0) {
    float v = clamp_logit(acc + b[0]);
    if (read_mask(mask, row, mmode[0])) v = -INFINITY;
    logits[row] = v;
  }
}

// pa_np logits over (N, L+1): rows l<L from X (bf16), row L from c (f32)
__global__ void k_logits_np(const bf16* __restrict__ X, const float* __restrict__ c,
                            const float* __restrict__ w, const float* __restrict__ b,
                            const void* __restrict__ mask, const int* __restrict__ mmode,
                            float* __restrict__ logits) {
  int row = blockIdx.x * blockDim.y + threadIdx.y;
  if (row >= NB * (LL + 1)) return;
  int n = row / (LL + 1), l = row % (LL + 1);
  int lane = threadIdx.x;
  float acc = 0.f;
  if (l < LL) {
    const bf16* xp = X + ((size_t)n * LL + l) * D_;
    for (int d = lane; d < D_; d += 64) acc += toF(xp[d]) * w[d];
  } else {
    const float* cp = c + n * D_;
    for (int d = lane; d < D_; d += 64) acc += cp[d] * w[d];
  }
#pragma unroll
  for (int off = 32; off; off >>= 1) acc += __shfl_down(acc, off);
  if (lane == 0) {
    float v = clamp_logit(acc + b[0]);
    if (read_mask(mask, row, mmode[0])) v = -INFINITY;
    logits[row] = v;
  }
}

// ---------------- softmax over L + weighted sum of t2 rows -> u1[n,:] ----------------
__global__ __launch_bounds__(256) void k_soft_u1(const float* __restrict__ logits,
                                                 const float* __restrict__ t2,
                                                 float* __restrict__ u1) {
  int n = blockIdx.x, tid = threadIdx.x;
  __shared__ float w[LL];
  __shared__ float red[4];
  __shared__ float stat;
  float m = -INFINITY;
  for (int l = tid; l < LL; l += 256) { float v = logits[n * LL + l]; w[l] = v; m = fmaxf(m, v); }
#pragma unroll
  for (int off = 32; off; off >>= 1) m = fmaxf(m, __shfl_down(m, off));
  if ((tid & 63) == 0) red[tid >> 6] = m;
  __syncthreads();
  if (tid == 0) stat = fmaxf(fmaxf(red[0], red[1]), fmaxf(red[2], red[3]));
  __syncthreads();
  float M = stat;
  if (!(M > -INFINITY && M < INFINITY)) M = 0.f;
  float s = 0.f;
  for (int l = tid; l < LL; l += 256) { float p = __expf(w[l] - M); w[l] = p; s += p; }
#pragma unroll
  for (int off = 32; off; off >>= 1) s += __shfl_down(s, off);
  __syncthreads();
  if ((tid & 63) == 0) red[tid >> 6] = s;
  __syncthreads();
  if (tid == 0) stat = red[0] + red[1] + red[2] + red[3];
  __syncthreads();
  float inv = (stat > 0.f) ? 1.f / stat : 0.f;
  for (int d = tid; d < D_; d += 256) {
    float acc = 0.f;
    const float* tp = t2 + (size_t)n * LL * D_ + d;
    for (int l = 0; l < LL; ++l) acc += w[l] * tp[(size_t)l * D_];
    u1[n * D_ + d] = acc * inv;
  }
}

__global__ __launch_bounds__(256) void k_soft_u2(const float* __restrict__ logits,
                                                 const bf16* __restrict__ X,
                                                 const float* __restrict__ c,
                                                 float* __restrict__ u2) {
  int n = blockIdx.x, tid = threadIdx.x;
  __shared__ float w[LL + 1];
  __shared__ float red[4];
  __shared__ float stat;
  float m = -INFINITY;
  for (int l = tid; l < LL + 1; l += 256) { float v = logits[n * (LL + 1) + l]; w[l] = v; m = fmaxf(m, v); }
#pragma unroll
  for (int off = 32; off; off >>= 1) m = fmaxf(m, __shfl_down(m, off));
  if ((tid & 63) == 0) red[tid >> 6] = m;
  __syncthreads();
  if (tid == 0) stat = fmaxf(fmaxf(red[0], red[1]), fmaxf(red[2], red[3]));
  __syncthreads();
  float M = stat;
  if (!(M > -INFINITY && M < INFINITY)) M = 0.f;
  float s = 0.f;
  for (int l = tid; l < LL + 1; l += 256) { float p = __expf(w[l] - M); w[l] = p; s += p; }
#pragma unroll
  for (int off = 32; off; off >>= 1) s += __shfl_down(s, off);
  __syncthreads();
  if ((tid & 63) == 0) red[tid >> 6] = s;
  __syncthreads();
  if (tid == 0) stat = red[0] + red[1] + red[2] + red[3];
  __syncthreads();
  float inv = (stat > 0.f) ? 1.f / stat : 0.f;
  for (int d = tid; d < D_; d += 256) {
    float acc = 0.f;
    const bf16* xp = X + (size_t)n * LL * D_ + d;
    for (int l = 0; l < LL; ++l) acc += w[l] * toF(xp[(size_t)l * D_]);
    acc += w[LL] * c[n * D_ + d];
    u2[n * D_ + d] = acc * inv;
  }
}

// ---------------- wsrc[h,d] = sum_e W[d,h,e]*att_src[h,e] (and wdst) ----------------
__global__ void k_wvec(const float* __restrict__ W, const float* __restrict__ att_src,
                       const float* __restrict__ att_dst, float* __restrict__ wsrc,
                       float* __restrict__ wdst) {
  int idx = blockIdx.x * blockDim.x + threadIdx.x;
  if (idx >= 2 * H_ * D_) return;
  int s = idx / (H_ * D_);
  int r = idx % (H_ * D_);
  int h = r / D_, d = r % D_;
  const float* att = (s ? att_dst : att_src) + h * D_;
  const float* Wp = W + (size_t)d * H_ * D_ + h * D_;
  float acc = 0.f;
  for (int e = 0; e < D_; ++e) acc += Wp[e] * att[e];
  (s ? wdst : wsrc)[h * D_ + d] = acc;
}

// ---------------- a_src/a_dst[row,h] = x[row,:] . wvec[h,:] ----------------
template <typename T>
__global__ void k_asrc(const T* __restrict__ x, const float* __restrict__ wsrc,
                       const float* __restrict__ wdst, float* __restrict__ a_src,
                       float* __restrict__ a_dst, int rows) {
  int row = blockIdx.x * blockDim.y + threadIdx.y;
  if (row >= rows) return;
  int lane = threadIdx.x;
  const T* xp = x + (size_t)row * D_;
  float xr[5];
#pragma unroll
  for (int i = 0; i < 5; ++i) { int d = lane + 64 * i; xr[i] = (d < D_) ? toF(xp[d]) : 0.f; }
#pragma unroll
  for (int hh = 0; hh < H_; ++hh) {
    float as = 0.f, ad = 0.f;
#pragma unroll
    for (int i = 0; i < 5; ++i) {
      int d = lane + 64 * i;
      if (d < D_) { as += xr[i] * wsrc[hh * D_ + d]; ad += xr[i] * wdst[hh * D_ + d]; }
    }
#pragma unroll
    for (int off = 32; off; off >>= 1) { as += __shfl_down(as, off); ad += __shfl_down(ad, off); }
    if (lane == 0) { a_src[(size_t)row * H_ + hh] = as; a_dst[(size_t)row * H_ + hh] = ad; }
  }
}

// ---------------- pack W: (300 x 5 x 300, f32) -> Bp2 (320 x KP2, bf16, transposed) ----------------
// Bp2[n][k] = W[d_in=k%300][h=k/300][n] ; zero outside
__global__ void k_packB2(const float* __restrict__ W, bf16* __restrict__ Bp2) {
  int idx = blockIdx.x * 256 + threadIdx.x;
  if (idx >= 320 * KP2) return;
  int n = idx / KP2, k = idx - n * KP2;
  float v = 0.f;
  if (n < D_ && k < H_ * D_) {
    int h = k / D_, di = k - h * D_;
    v = W[(size_t)di * (H_ * D_) + h * D_ + n];
  }
  Bp2[idx] = f2bf(v);
}

// ---------------- per-node aggregation of x with edge-softmax alphas ----------------
// agg[node, h*300+d] = sum_{e: dst=node} alpha[e,h] * x[src_e, d] ; cols 1500..1535 zeroed
template <typename T>
__global__ __launch_bounds__(128) void k_agg(
    const T* __restrict__ x, const float* __restrict__ a_src, const float* __restrict__ a_dst,
    const int* __restrict__ edges, int estride, int E, int nodes, int g_off,
    bf16* __restrict__ agg) {
  int g = blockIdx.x / nodes;
  int node = blockIdx.x % nodes;
  int tid = threadIdx.x;
  __shared__ int elist[MAXDEG];
  __shared__ int slist[MAXDEG];
  __shared__ float al[MAXDEG][H_];
  __shared__ int cnt;
  if (tid == 0) cnt = 0;
  __syncthreads();
  const int* src = edges + (size_t)(g_off + g) * estride;
  const int* dst = src + E;
  for (int e = tid; e < E; e += 128) {
    if (dst[e] == node) {
      int p = atomicAdd(&cnt, 1);
      if (p < MAXDEG) elist[p] = e;
    }
  }
  __syncthreads();
  int deg = cnt < MAXDEG ? cnt : MAXDEG;
  for (int i = tid; i < deg; i += 128) slist[i] = src[elist[i]];
  __syncthreads();
  const float* adr = a_dst + ((size_t)g * nodes + node) * H_;
  for (int i = tid; i < deg * H_; i += 128) {
    int ei = i / H_, hh = i - ei * H_;
    float v = a_src[((size_t)g * nodes + slist[ei]) * H_ + hh] + adr[hh];
    al[ei][hh] = v > 0.f ? v : 0.2f * v;
  }
  __syncthreads();
  if (tid < H_) {
    float m = -INFINITY;
    for (int i = 0; i < deg; ++i) m = fmaxf(m, al[i][tid]);
    float s = 0.f;
    for (int i = 0; i < deg; ++i) { float p = __expf(al[i][tid] - m); al[i][tid] = p; s += p; }
    float inv = 1.f / (s + 1e-16f);
    for (int i = 0; i < deg; ++i) al[i][tid] *= inv;
  }
  __syncthreads();
  bf16* arow = agg + (size_t)(g * nodes + node) * KP2;
#pragma unroll
  for (int t = 0; t < 3; ++t) {
    int d = tid + t * 128;
    if (d < D_) {
      float o0 = 0.f, o1 = 0.f, o2 = 0.f, o3 = 0.f, o4 = 0.f;
      for (int i = 0; i < deg; ++i) {
        float xv = toF(x[((size_t)g * nodes + slist[i]) * D_ + d]);
        o0 += al[i][0] * xv; o1 += al[i][1] * xv; o2 += al[i][2] * xv;
        o3 += al[i][3] * xv; o4 += al[i][4] * xv;
      }
      arow[0 * D_ + d] = f2bf(o0); arow[1 * D_ + d] = f2bf(o1);
      arow[2 * D_ + d] = f2bf(o2); arow[3 * D_ + d] = f2bf(o3);
      arow[4 * D_ + d] = f2bf(o4);
    }
  }
  if (tid < KP2 - H_ * D_) arow[H_ * D_ + tid] = f2bf(0.f);
}

// ---------------- MFMA GEMM + fused bias/mask/relu/LayerNorm ----------------
// out_row = LN(relu(mask(agg_row @ Bp2^T * (1/H) + bias))) -> Xout (M x 300 bf16)
// block: 256 thr (4 waves), BM=128 rows, all 320 cols; K = KP2.
__global__ __launch_bounds__(256) void k_gemm_ln(
    const bf16* __restrict__ agg, const bf16* __restrict__ Bp2,
    const float* __restrict__ bias, const float* __restrict__ lng, const float* __restrict__ lnb,
    const void* __restrict__ gmask, const int* __restrict__ mmode, int g_off, int nodes,
    int M, bf16* __restrict__ Xout) {
  __shared__ short As[128][40];
  __shared__ short Bs[320][40];
  int m0 = blockIdx.x * 128;
  int tid = threadIdx.x;
  int wave = tid >> 6, lane = tid & 63;
  int wr = wave * 32;
  int cl = lane & 15, q = lane >> 4;
  f32x4 acc[2][NT] = {};
  for (int k0 = 0; k0 < KP2; k0 += 32) {
    // stage A: 128 rows x 32 k
#pragma unroll
    for (int cc = 0; cc < 2; ++cc) {
      int c = tid + cc * 256;
      int m = c >> 2, ko = (c & 3) << 3;
      int row = m0 + m; if (row >= M) row = M - 1;
      *(uint4*)&As[m][ko] = *(const uint4*)(agg + (size_t)row * KP2 + k0 + ko);
    }
    // stage B: 320 rows x 32 k
#pragma unroll
    for (int cc = 0; cc < 5; ++cc) {
      int c = tid + cc * 256;
      int n = c >> 2, ko = (c & 3) << 3;
      *(uint4*)&Bs[n][ko] = *(const uint4*)(Bp2 + (size_t)n * KP2 + k0 + ko);
    }
    __syncthreads();
    int kq = q << 3;
    short8 af0 = *(const short8*)&As[wr + cl][kq];
    short8 af1 = *(const short8*)&As[wr + 16 + cl][kq];
#pragma unroll
    for (int j = 0; j < NT; ++j) {
      short8 bfr = *(const short8*)&Bs[j * 16 + cl][kq];
      acc[0][j] = __builtin_amdgcn_mfma_f32_16x16x32_bf16(af0, bfr, acc[0][j], 0, 0, 0);
      acc[1][j] = __builtin_amdgcn_mfma_f32_16x16x32_bf16(af1, bfr, acc[1][j], 0, 0, 0);
    }
    __syncthreads();
  }
  // epilogue: lane holds rows (wr + i*16 + q*4 + r), cols (j*16 + cl)
  int mode = mmode[0];
#pragma unroll
  for (int i = 0; i < 2; ++i) {
#pragma unroll
    for (int r = 0; r < 4; ++r) {
      int row = m0 + wr + i * 16 + q * 4 + r;
      bool rowok = row < M;
      int rr = rowok ? row : M - 1;
      int grph = rr / nodes;
      int mk = gmask ? read_mask(gmask, g_off + grph, mode) : 0;
      float s = 0.f, sq = 0.f;
#pragma unroll
      for (int j = 0; j < NT; ++j) {
        int col = j * 16 + cl;
        bool valid = col < D_;
        float v = 0.f;
        if (valid) {
          v = acc[i][j][r] * 0.2f + bias[col];
          if (mk) v = 0.f;
          v = fmaxf(v, 0.f);
        }
        s += v; sq += v * v;
      }
#pragma unroll
      for (int off = 1; off < 16; off <<= 1) {
        s += __shfl_xor(s, off); sq += __shfl_xor(sq, off);
      }
      float mu = s * (1.f / 300.f);
      float var = sq * (1.f / 300.f) - mu * mu;
      var = fmaxf(var, 0.f);
      float rstd = rsqrtf(var + 1e-5f);
      if (rowok) {
#pragma unroll
        for (int j = 0; j < NT; ++j) {
          int col = j * 16 + cl;
          if (col < D_) {
            float v = acc[i][j][r] * 0.2f + bias[col];
            if (mk) v = 0.f;
            v = fmaxf(v, 0.f);
            float o = (v - mu) * rstd * lng[col] + lnb[col];
            Xout[(size_t)row * D_ + col] = f2bf(o);
          }
        }
      }
    }
  }
}

// ---------------- final: out[n, k]=a1, out[n, K+k]=a2 (f32 out) ----------------
__global__ void k_out(const float* __restrict__ u1, const float* __restrict__ u2,
                      const float* __restrict__ v2, const bf16* __restrict__ v3,
                      float* __restrict__ out) {
  int idx = blockIdx.x * blockDim.y + threadIdx.y;
  if (idx >= NB * KK) return;
  int n = idx / KK, k = idx - n * KK;
  int lane = threadIdx.x;
  const float* ap = v2 + (size_t)idx * D_;
  const bf16* bp = v3 + (size_t)idx * D_;
  const float* u1p = u1 + n * D_;
  const float* u2p = u2 + n * D_;
  float a1 = 0.f, a2 = 0.f;
  for (int d = lane; d < D_; d += 64) { a1 += u1p[d] * ap[d]; a2 += u2p[d] * toF(bp[d]); }
#pragma unroll
  for (int off = 32; off; off >>= 1) { a1 += __shfl_down(a1, off); a2 += __shfl_down(a2, off); }
  if (lane == 0) {
    const float scale = 0.05773502691896258f;  // 1/sqrt(300)
    out[(size_t)n * 2 * KK + k] = a1 * scale;
    out[(size_t)n * 2 * KK + KK + k] = a2 * scale;
  }
}

extern "C" void kernel_launch(void* const* d_in, const int* in_sizes, int n_in,
                              void* d_out, int out_size, void* d_ws, size_t ws_size,
                              hipStream_t stream) {
  const float* t2    = (const float*)d_in[0];
  const float* v2    = (const float*)d_in[1];
  const float* score = (const float*)d_in[2];
  const int*   eidx  = (const int*)d_in[3];
  const void*  gmask = d_in[4];
  const void*  kpm   = d_in[5];
  const void*  npm   = d_in[6];
  const int*   iedge = (const int*)d_in[7];
  const float* txtW  = (const float*)d_in[8];
  const float* txtAs = (const float*)d_in[9];
  const float* txtAd = (const float*)d_in[10];
  const float* txtB  = (const float*)d_in[11];
  const float* imgW  = (const float*)d_in[12];
  const float* imgAs = (const float*)d_in[13];
  const float* imgAd = (const float*)d_in[14];
  const float* imgB  = (const float*)d_in[15];
  const float* w1    = (const float*)d_in[16];
  const float* b1    = (const float*)d_in[17];
  const float* w2    = (const float*)d_in[18];
  const float* b2    = (const float*)d_in[19];
  const float* lng   = (const float*)d_in[20];
  const float* lnb   = (const float*)d_in[21];
  float* out = (float*)d_out;

  char* ws = (char*)d_ws;
  size_t off = 0;
  auto alloc = [&](size_t bytes) -> char* {
    char* p = ws + off;
    off += (bytes + 511) & ~(size_t)511;
    return p;
  };
  int*   mmode = (int*)alloc(64);
  float* c    = (float*)alloc((size_t)NB * D_ * 4);
  float* u1   = (float*)alloc((size_t)NB * D_ * 4);
  float* u2   = (float*)alloc((size_t)NB * D_ * 4);
  float* lg1  = (float*)alloc((size_t)NB * LL * 4);
  float* lg2  = (float*)alloc((size_t)NB * (LL + 1) * 4);
  float* wsrc = (float*)alloc((size_t)H_ * D_ * 4);
  float* wdst = (float*)alloc((size_t)H_ * D_ * 4);
  float* asrc = (float*)alloc((size_t)NB * LL * H_ * 4);
  float* adst = (float*)alloc((size_t)NB * LL * H_ * 4);
  bf16* X   = (bf16*)alloc((size_t)NB * LL * D_ * 2);   // txt state (in-place across layers)
  bf16* V   = (bf16*)alloc((size_t)NB * KK * D_ * 2);   // img state (in-place across layers)
  bf16* Bp2 = (bf16*)alloc((size_t)320 * KP2 * 2);      // packed/transposed weights
  size_t havail = (ws_size > off) ? (ws_size - off) : 0;
  bf16* agg = (bf16*)(ws + off);
  size_t per_g_txt = (size_t)LL * KP2 * 2;
  int cg = (int)(havail / per_g_txt);
  if (cg < 1) cg = 1;
  if (cg > NB) cg = NB;
  size_t per_g_img = (size_t)KK * KP2 * 2;
  int cgi = (int)(havail / per_g_img);
  if (cgi < 1) cgi = 1;
  if (cgi > NB) cgi = NB;

  dim3 b64x4(64, 4);

  k_detect<<<1, 256, 0, stream>>>((const unsigned int*)kpm, NB * LL / 4, mmode);

  // phase 0: c, pa_token softmax -> u1
  k_c<<<dim3(NB, 3), 128, 0, stream>>>(t2, score, c);
  k_logits_tok<<<(NB * LL + 3) / 4, b64x4, 0, stream>>>(t2, w1, b1, kpm, mmode, lg1, NB * LL);
  k_soft_u1<<<NB, 256, 0, stream>>>(lg1, t2, u1);

  // text GAT (2 layers), chunked over graphs, in-place on X
  for (int layer = 0; layer < 2; ++layer) {
    const float* W = txtW + (size_t)layer * D_ * H_ * D_;
    k_packB2<<<(320 * KP2 + 255) / 256, 256, 0, stream>>>(W, Bp2);
    k_wvec<<<(2 * H_ * D_ + 255) / 256, 256, 0, stream>>>(
        W, txtAs + layer * H_ * D_, txtAd + layer * H_ * D_, wsrc, wdst);
    for (int g0 = 0; g0 < NB; g0 += cg) {
      int gs = (cg < NB - g0) ? cg : (NB - g0);
      int M = gs * LL;
      bf16* Xout = X + (size_t)g0 * LL * D_;
      if (layer == 0) {
        const float* Xin = t2 + (size_t)g0 * LL * D_;
        k_asrc<float><<<(M + 3) / 4, b64x4, 0, stream>>>(Xin, wsrc, wdst, asrc, adst, M);
        k_agg<float><<<M, 128, 0, stream>>>(Xin, asrc, adst, eidx, 2 * ETXT, ETXT, LL, g0, agg);
      } else {
        const bf16* Xin = X + (size_t)g0 * LL * D_;
        k_asrc<bf16><<<(M + 3) / 4, b64x4, 0, stream>>>(Xin, wsrc, wdst, asrc, adst, M);
        k_agg<bf16><<<M, 128, 0, stream>>>(Xin, asrc, adst, eidx, 2 * ETXT, ETXT, LL, g0, agg);
      }
      k_gemm_ln<<<(M + 127) / 128, 256, 0, stream>>>(
          agg, Bp2, txtB + layer * D_, lng, lnb, gmask, mmode, g0, LL, M, Xout);
    }
  }

  // image GAT (2 layers), shared edges, no gnn_mask, in-place on V
  for (int layer = 0; layer < 2; ++layer) {
    const float* W = imgW + (size_t)layer * D_ * H_ * D_;
    k_packB2<<<(320 * KP2 + 255) / 256, 256, 0, stream>>>(W, Bp2);
    k_wvec<<<(2 * H_ * D_ + 255) / 256, 256, 0, stream>>>(
        W, imgAs + layer * H_ * D_, imgAd + layer * H_ * D_, wsrc, wdst);
    for (int g0 = 0; g0 < NB; g0 += cgi) {
      int gs = (cgi < NB - g0) ? cgi : (NB - g0);
      int M = gs * KK;
      bf16* Vout = V + (size_t)g0 * KK * D_;
      if (layer == 0) {
        const float* Vin = v2 + (size_t)g0 * KK * D_;
        k_asrc<float><<<(M + 3) / 4, b64x4, 0, stream>>>(Vin, wsrc, wdst, asrc, adst, M);
        k_agg<float><<<M, 128, 0, stream>>>(Vin, asrc, adst, iedge, 0, EIMG, KK, 0, agg);
      } else {
        const bf16* Vin = V + (size_t)g0 * KK * D_;
        k_asrc<bf16><<<(M + 3) / 4, b64x4, 0, stream>>>(Vin, wsrc, wdst, asrc, adst, M);
        k_agg<bf16><<<M, 128, 0, stream>>>(Vin, asrc, adst, iedge, 0, EIMG, KK, 0, agg);
      }
      k_gemm_ln<<<(M + 127) / 128, 256, 0, stream>>>(
          agg, Bp2, imgB + layer * D_, lng, lnb, nullptr, mmode, 0, KK, M, Vout);
    }
  }

  // epilogue: pa_np softmax -> u2, then a1/a2
  k_logits_np<<<(NB * (LL + 1) + 3) / 4, b64x4, 0, stream>>>(X, c, w2, b2, npm, mmode, lg2);
  k_soft_u2<<<NB, 256, 0, stream>>>(lg2, X, c, u2);
  k_out<<<(NB * KK + 3) / 4, b64x4, 0, stream>>>(u1, u2, v2, V, out);
}

// Round 6
// 1409.141 us; speedup vs baseline: 1.0691x; 1.0691x over previous
//
#include <hip/hip_runtime.h>
#include <hip/hip_bf16.h>
#include <math.h>

typedef __hip_bfloat16 bf16;
__device__ __forceinline__ float toF(float v){ return v; }
__device__ __forceinline__ float toF(bf16 v){ return __bfloat162float(v); }
__device__ __forceinline__ bf16 f2bf(float v){ return __float2bfloat16(v); }

#define D_    300
#define H_    5
#define NB    64
#define LL    1024
#define KK    64
#define ETXT  2048
#define EIMG  512
#define MAXDEG 128
#define KP2   1536   // agg row width: H*D=1500 padded to 48*32

typedef __attribute__((ext_vector_type(8))) short short8;
typedef __attribute__((ext_vector_type(4))) float f32x4;

// Mask storage modes: 0 = 4-byte word, 1 = 2-byte, 2 = 1-byte (bool), 3 = 8-byte.
__device__ __forceinline__ int read_mask(const void* p, int i, int mode) {
  switch (mode) {
    case 1: return ((const unsigned short*)p)[i] != 0;
    case 2: return ((const unsigned char*)p)[i] != 0;
    case 3: { const unsigned int* w = (const unsigned int*)p;
              return (w[2*i] | w[2*i+1]) != 0; }
    default: return ((const unsigned int*)p)[i] != 0;
  }
}

__global__ void k_detect(const unsigned int* __restrict__ w, int nwords,
                         int* __restrict__ mode) {
  __shared__ unsigned int se[256], so[256];
  unsigned int oe = 0, oo = 0;
  for (int i = threadIdx.x; i < nwords; i += 256) {
    unsigned int v = w[i];
    if (i & 1) oo |= v; else oe |= v;
  }
  se[threadIdx.x] = oe; so[threadIdx.x] = oo;
  __syncthreads();
  for (int s = 128; s; s >>= 1) {
    if (threadIdx.x < s) { se[threadIdx.x] |= se[threadIdx.x+s]; so[threadIdx.x] |= so[threadIdx.x+s]; }
    __syncthreads();
  }
  if (threadIdx.x == 0) {
    unsigned int O = se[0] | so[0];
    int m = 0;
    if (O == 0u) m = 0;
    else if ((O & 0xFFFFu) == 0x3F80u) m = 1;
    else if ((O >> 16) == 0x3F80u && (O & 0xFFFFu) == 0u) m = 0;
    else if ((O >> 16) == 0x3FF0u) m = 3;
    else if (O <= 1u) m = (so[0] == 0u && se[0] != 0u) ? 3 : 0;
    else if ((O & 0xFEFEFEFEu) == 0u) m = 2;
    mode[0] = m;
  }
}

__global__ void k_zero(float* __restrict__ a, float* __restrict__ b,
                       float* __restrict__ cc, int n) {
  int i = blockIdx.x * 256 + threadIdx.x;
  if (i < n) { a[i] = 0.f; b[i] = 0.f; cc[i] = 0.f; }
}

__device__ __forceinline__ float clamp_logit(float v) {
  if (!(v > -1e30f)) v = -1e30f;
  if (v > 1e30f) v = 1e30f;
  return v;
}

// ---------------- CSR build: one block per graph ----------------
__global__ __launch_bounds__(256) void k_csr(const int* __restrict__ edges, int estride,
                                             int E, int nodes,
                                             int* __restrict__ csr, int* __restrict__ off) {
  int g = blockIdx.x;
  const int* src = edges + (size_t)g * estride;
  const int* dst = src + E;
  __shared__ int cnt[1024];
  __shared__ int pos[1024];
  __shared__ int bsum[256];
  int tid = threadIdx.x;
  for (int i = tid; i < nodes; i += 256) cnt[i] = 0;
  __syncthreads();
  for (int e = tid; e < E; e += 256) atomicAdd(&cnt[dst[e]], 1);
  __syncthreads();
  int per = (nodes + 255) / 256;
  int s = 0;
  for (int k = 0; k < per; ++k) { int i = tid * per + k; if (i < nodes) s += cnt[i]; }
  bsum[tid] = s;
  __syncthreads();
  if (tid == 0) { int a = 0; for (int i = 0; i < 256; ++i) { int t = bsum[i]; bsum[i] = a; a += t; } }
  __syncthreads();
  s = bsum[tid];
  for (int k = 0; k < per; ++k) {
    int i = tid * per + k;
    if (i < nodes) { pos[i] = s; int t = cnt[i]; cnt[i] = s; s += t; }
  }
  __syncthreads();
  for (int i = tid; i < nodes; i += 256) off[(size_t)g * (nodes + 1) + i] = cnt[i];
  if (tid == 0) off[(size_t)g * (nodes + 1) + nodes] = E;
  for (int e = tid; e < E; e += 256) {
    int p = atomicAdd(&pos[dst[e]], 1);
    csr[(size_t)g * E + p] = src[e];
  }
}

// ---------------- pa_token logits (wave per row) ----------------
__global__ void k_logits_tok(const float* __restrict__ x, const float* __restrict__ w,
                             const float* __restrict__ b, const void* __restrict__ mask,
                             const int* __restrict__ mmode,
                             float* __restrict__ logits, int rows) {
  int row = blockIdx.x * blockDim.y + threadIdx.y;
  if (row >= rows) return;
  int lane = threadIdx.x;
  const float* xp = x + (size_t)row * D_;
  float acc = 0.f;
  for (int d = lane; d < D_; d += 64) acc += xp[d] * w[d];
#pragma unroll
  for (int off = 32; off; off >>= 1) acc += __shfl_down(acc, off);
  if (lane == 0) {
    float v = clamp_logit(acc + b[0]);
    if (read_mask(mask, row, mmode[0])) v = -INFINITY;
    logits[row] = v;
  }
}

// pa_np logits over (N, L+1)
__global__ void k_logits_np(const bf16* __restrict__ X, const float* __restrict__ c,
                            const float* __restrict__ w, const float* __restrict__ b,
                            const void* __restrict__ mask, const int* __restrict__ mmode,
                            float* __restrict__ logits) {
  int row = blockIdx.x * blockDim.y + threadIdx.y;
  if (row >= NB * (LL + 1)) return;
  int n = row / (LL + 1), l = row % (LL + 1);
  int lane = threadIdx.x;
  float acc = 0.f;
  if (l < LL) {
    const bf16* xp = X + ((size_t)n * LL + l) * D_;
    for (int d = lane; d < D_; d += 64) acc += toF(xp[d]) * w[d];
  } else {
    const float* cp = c + n * D_;
    for (int d = lane; d < D_; d += 64) acc += cp[d] * w[d];
  }
#pragma unroll
  for (int off = 32; off; off >>= 1) acc += __shfl_down(acc, off);
  if (lane == 0) {
    float v = clamp_logit(acc + b[0]);
    if (read_mask(mask, row, mmode[0])) v = -INFINITY;
    logits[row] = v;
  }
}

// ---------------- in-place softmax probs over a row of `len` ----------------
__global__ __launch_bounds__(256) void k_probs(float* __restrict__ lg, int len) {
  int n = blockIdx.x, tid = threadIdx.x;
  __shared__ float w[LL + 1];
  __shared__ float red[4];
  __shared__ float stat;
  float m = -INFINITY;
  for (int l = tid; l < len; l += 256) { float v = lg[n * len + l]; w[l] = v; m = fmaxf(m, v); }
#pragma unroll
  for (int off = 32; off; off >>= 1) m = fmaxf(m, __shfl_down(m, off));
  if ((tid & 63) == 0) red[tid >> 6] = m;
  __syncthreads();
  if (tid == 0) stat = fmaxf(fmaxf(red[0], red[1]), fmaxf(red[2], red[3]));
  __syncthreads();
  float M = stat;
  if (!(M > -INFINITY && M < INFINITY)) M = 0.f;
  float s = 0.f;
  for (int l = tid; l < len; l += 256) { float p = __expf(w[l] - M); w[l] = p; s += p; }
#pragma unroll
  for (int off = 32; off; off >>= 1) s += __shfl_down(s, off);
  __syncthreads();
  if ((tid & 63) == 0) red[tid >> 6] = s;
  __syncthreads();
  if (tid == 0) stat = red[0] + red[1] + red[2] + red[3];
  __syncthreads();
  float inv = (stat > 0.f) ? 1.f / stat : 0.f;
  for (int l = tid; l < len; l += 256) lg[n * len + l] = w[l] * inv;
}

// ---------------- split-L partial sums: c += t2*score, u1 += p1*t2 ----------------
__global__ __launch_bounds__(128) void k_cu1(const float* __restrict__ t2,
                                             const float* __restrict__ score,
                                             const float* __restrict__ probs,
                                             float* __restrict__ c, float* __restrict__ u1) {
  int n = blockIdx.x, lc = blockIdx.y, tid = threadIdx.x;
  float aC[3] = {0.f, 0.f, 0.f}, aU[3] = {0.f, 0.f, 0.f};
  const float* base = t2 + (size_t)n * LL * D_;
  const float* sbase = score + (size_t)n * LL * D_;
  for (int l = lc * 128; l < lc * 128 + 128; ++l) {
    float w = probs[n * LL + l];
    const float* tp = base + (size_t)l * D_;
    const float* sp = sbase + (size_t)l * D_;
#pragma unroll
    for (int t = 0; t < 3; ++t) {
      int d = tid + t * 128;
      if (d < D_) { float tv = tp[d]; aC[t] += tv * sp[d]; aU[t] += w * tv; }
    }
  }
#pragma unroll
  for (int t = 0; t < 3; ++t) {
    int d = tid + t * 128;
    if (d < D_) { atomicAdd(c + n * D_ + d, aC[t]); atomicAdd(u1 + n * D_ + d, aU[t]); }
  }
}

// ---------------- split-L partial sums: u2 += p2*X (l < L only) ----------------
__global__ __launch_bounds__(128) void k_u2(const bf16* __restrict__ X,
                                            const float* __restrict__ probs2,
                                            float* __restrict__ u2) {
  int n = blockIdx.x, lc = blockIdx.y, tid = threadIdx.x;
  float aU[3] = {0.f, 0.f, 0.f};
  const bf16* base = X + (size_t)n * LL * D_;
  for (int l = lc * 128; l < lc * 128 + 128; ++l) {
    float w = probs2[n * (LL + 1) + l];
    const bf16* xp = base + (size_t)l * D_;
#pragma unroll
    for (int t = 0; t < 3; ++t) {
      int d = tid + t * 128;
      if (d < D_) aU[t] += w * toF(xp[d]);
    }
  }
#pragma unroll
  for (int t = 0; t < 3; ++t) {
    int d = tid + t * 128;
    if (d < D_) atomicAdd(u2 + n * D_ + d, aU[t]);
  }
}

// ---------------- wsrc[h,d] = sum_e W[d,h,e]*att_src[h,e] (and wdst) ----------------
__global__ void k_wvec(const float* __restrict__ W, const float* __restrict__ att_src,
                       const float* __restrict__ att_dst, float* __restrict__ wsrc,
                       float* __restrict__ wdst) {
  int idx = blockIdx.x * blockDim.x + threadIdx.x;
  if (idx >= 2 * H_ * D_) return;
  int s = idx / (H_ * D_);
  int r = idx % (H_ * D_);
  int h = r / D_, d = r % D_;
  const float* att = (s ? att_dst : att_src) + h * D_;
  const float* Wp = W + (size_t)d * H_ * D_ + h * D_;
  float acc = 0.f;
  for (int e = 0; e < D_; ++e) acc += Wp[e] * att[e];
  (s ? wdst : wsrc)[h * D_ + d] = acc;
}

// ---------------- a_src/a_dst[row,h] = x[row,:] . wvec[h,:] ----------------
template <typename T>
__global__ void k_asrc(const T* __restrict__ x, const float* __restrict__ wsrc,
                       const float* __restrict__ wdst, float* __restrict__ a_src,
                       float* __restrict__ a_dst, int rows) {
  int row = blockIdx.x * blockDim.y + threadIdx.y;
  if (row >= rows) return;
  int lane = threadIdx.x;
  const T* xp = x + (size_t)row * D_;
  float xr[5];
#pragma unroll
  for (int i = 0; i < 5; ++i) { int d = lane + 64 * i; xr[i] = (d < D_) ? toF(xp[d]) : 0.f; }
#pragma unroll
  for (int hh = 0; hh < H_; ++hh) {
    float as = 0.f, ad = 0.f;
#pragma unroll
    for (int i = 0; i < 5; ++i) {
      int d = lane + 64 * i;
      if (d < D_) { as += xr[i] * wsrc[hh * D_ + d]; ad += xr[i] * wdst[hh * D_ + d]; }
    }
#pragma unroll
    for (int off = 32; off; off >>= 1) { as += __shfl_down(as, off); ad += __shfl_down(ad, off); }
    if (lane == 0) { a_src[(size_t)row * H_ + hh] = as; a_dst[(size_t)row * H_ + hh] = ad; }
  }
}

// ---------------- pack W: (300 x 5 x 300, f32) -> Bp2 (320 x KP2, bf16, transposed) ----------------
__global__ void k_packB2(const float* __restrict__ W, bf16* __restrict__ Bp2) {
  int idx = blockIdx.x * 256 + threadIdx.x;
  if (idx >= 320 * KP2) return;
  int n = idx / KP2, k = idx - n * KP2;
  float v = 0.f;
  if (n < D_ && k < H_ * D_) {
    int h = k / D_, di = k - h * D_;
    v = W[(size_t)di * (H_ * D_) + h * D_ + n];
  }
  Bp2[idx] = f2bf(v);
}

// ---------------- per-node aggregation of x with edge-softmax alphas (CSR) ----------------
template <typename T>
__global__ __launch_bounds__(128) void k_agg(
    const T* __restrict__ x, const float* __restrict__ a_src, const float* __restrict__ a_dst,
    const int* __restrict__ csr, const int* __restrict__ off, int E, int nodes,
    int g_glob0, int per_graph, bf16* __restrict__ agg) {
  int g = blockIdx.x / nodes;
  int node = blockIdx.x % nodes;
  int gg = per_graph ? (g_glob0 + g) : 0;
  int tid = threadIdx.x;
  __shared__ int slist[MAXDEG];
  __shared__ float al[MAXDEG][H_];
  int o0 = off[(size_t)gg * (nodes + 1) + node];
  int deg = off[(size_t)gg * (nodes + 1) + node + 1] - o0;
  if (deg > MAXDEG) deg = MAXDEG;
  for (int i = tid; i < deg; i += 128) slist[i] = csr[(size_t)gg * E + o0 + i];
  __syncthreads();
  const float* adr = a_dst + ((size_t)g * nodes + node) * H_;
  for (int i = tid; i < deg * H_; i += 128) {
    int ei = i / H_, hh = i - ei * H_;
    float v = a_src[((size_t)g * nodes + slist[ei]) * H_ + hh] + adr[hh];
    al[ei][hh] = v > 0.f ? v : 0.2f * v;
  }
  __syncthreads();
  if (tid < H_) {
    float m = -INFINITY;
    for (int i = 0; i < deg; ++i) m = fmaxf(m, al[i][tid]);
    float s = 0.f;
    for (int i = 0; i < deg; ++i) { float p = __expf(al[i][tid] - m); al[i][tid] = p; s += p; }
    float inv = 1.f / (s + 1e-16f);
    for (int i = 0; i < deg; ++i) al[i][tid] *= inv;
  }
  __syncthreads();
  bf16* arow = agg + (size_t)(g * nodes + node) * KP2;
#pragma unroll
  for (int t = 0; t < 3; ++t) {
    int d = tid + t * 128;
    if (d < D_) {
      float o0v = 0.f, o1 = 0.f, o2 = 0.f, o3 = 0.f, o4 = 0.f;
      for (int i = 0; i < deg; ++i) {
        float xv = toF(x[((size_t)g * nodes + slist[i]) * D_ + d]);
        o0v += al[i][0] * xv; o1 += al[i][1] * xv; o2 += al[i][2] * xv;
        o3 += al[i][3] * xv; o4 += al[i][4] * xv;
      }
      arow[0 * D_ + d] = f2bf(o0v); arow[1 * D_ + d] = f2bf(o1);
      arow[2 * D_ + d] = f2bf(o2); arow[3 * D_ + d] = f2bf(o3);
      arow[4 * D_ + d] = f2bf(o4);
    }
  }
  if (tid < KP2 - H_ * D_) arow[H_ * D_ + tid] = f2bf(0.f);
}

// ---------------- MFMA GEMM + fused bias/mask/relu/LayerNorm ----------------
// BM=64 rows, BN=320 cols, 256 thr = 4 waves; wave w: rows 0..63 (4 frags), cols w*80 (5 frags).
__global__ __launch_bounds__(256) void k_gemm_ln(
    const bf16* __restrict__ agg, const bf16* __restrict__ Bp2,
    const float* __restrict__ bias, const float* __restrict__ lng, const float* __restrict__ lnb,
    const void* __restrict__ gmask, const int* __restrict__ mmode, int g_off, int nodes,
    int M, bf16* __restrict__ Xout) {
  __shared__ short As[64][40];
  __shared__ short Bs[320][40];
  int m0 = blockIdx.x * 64;
  int tid = threadIdx.x;
  int wave = tid >> 6, lane = tid & 63;
  int wc = wave * 80;
  int cl = lane & 15, q = lane >> 4;
  f32x4 acc[4][5] = {};
  for (int k0 = 0; k0 < KP2; k0 += 32) {
    {
      int c = tid;                        // 256 uint4 = A tile
      int m = c >> 2, ko = (c & 3) << 3;
      int row = m0 + m; if (row >= M) row = M - 1;
      *(uint4*)&As[m][ko] = *(const uint4*)(agg + (size_t)row * KP2 + k0 + ko);
    }
#pragma unroll
    for (int cc = 0; cc < 5; ++cc) {      // 1280 uint4 = B tile
      int c = tid + cc * 256;
      int n = c >> 2, ko = (c & 3) << 3;
      *(uint4*)&Bs[n][ko] = *(const uint4*)(Bp2 + (size_t)n * KP2 + k0 + ko);
    }
    __syncthreads();
    int kq = q << 3;
    short8 af[4];
#pragma unroll
    for (int i = 0; i < 4; ++i) af[i] = *(const short8*)&As[i * 16 + cl][kq];
#pragma unroll
    for (int j = 0; j < 5; ++j) {
      short8 bfr = *(const short8*)&Bs[wc + j * 16 + cl][kq];
#pragma unroll
      for (int i = 0; i < 4; ++i)
        acc[i][j] = __builtin_amdgcn_mfma_f32_16x16x32_bf16(af[i], bfr, acc[i][j], 0, 0, 0);
    }
    __syncthreads();
  }
  // ---- epilogue: cross-wave LN ----
  float* sred = (float*)&As[0][0];       // [64][4]
  float* qred = sred + 64 * 4;           // [64][4]  (fits in As: 2KB < 5KB)
  int mode = mmode[0];
#pragma unroll
  for (int i = 0; i < 4; ++i) {
#pragma unroll
    for (int r = 0; r < 4; ++r) {
      int lrow = i * 16 + q * 4 + r;
      int row = m0 + lrow;
      int rr = row < M ? row : M - 1;
      int mk = gmask ? read_mask(gmask, g_off + rr / nodes, mode) : 0;
      float s = 0.f, sq = 0.f;
#pragma unroll
      for (int j = 0; j < 5; ++j) {
        int col = wc + j * 16 + cl;
        float v = 0.f;
        if (col < D_) {
          v = acc[i][j][r] * 0.2f + bias[col];
          if (mk) v = 0.f;
          v = fmaxf(v, 0.f);
        }
        s += v; sq += v * v;
      }
#pragma unroll
      for (int o2 = 1; o2 < 16; o2 <<= 1) { s += __shfl_xor(s, o2); sq += __shfl_xor(sq, o2); }
      if (cl == 0) { sred[lrow * 4 + wave] = s; qred[lrow * 4 + wave] = sq; }
    }
  }
  __syncthreads();
#pragma unroll
  for (int i = 0; i < 4; ++i) {
#pragma unroll
    for (int r = 0; r < 4; ++r) {
      int lrow = i * 16 + q * 4 + r;
      int row = m0 + lrow;
      if (row >= M) continue;
      float s = sred[lrow * 4 + 0] + sred[lrow * 4 + 1] + sred[lrow * 4 + 2] + sred[lrow * 4 + 3];
      float sq = qred[lrow * 4 + 0] + qred[lrow * 4 + 1] + qred[lrow * 4 + 2] + qred[lrow * 4 + 3];
      int mk = gmask ? read_mask(gmask, g_off + row / nodes, mode) : 0;
      float mu = s * (1.f / 300.f);
      float var = sq * (1.f / 300.f) - mu * mu;
      var = fmaxf(var, 0.f);
      float rstd = rsqrtf(var + 1e-5f);
#pragma unroll
      for (int j = 0; j < 5; ++j) {
        int col = wc + j * 16 + cl;
        if (col < D_) {
          float v = acc[i][j][r] * 0.2f + bias[col];
          if (mk) v = 0.f;
          v = fmaxf(v, 0.f);
          float o = (v - mu) * rstd * lng[col] + lnb[col];
          Xout[(size_t)row * D_ + col] = f2bf(o);
        }
      }
    }
  }
}

// ---------------- final: out[n,k]=a1, out[n,K+k]=a2 ----------------
__global__ void k_out(const float* __restrict__ u1, const float* __restrict__ u2,
                      const float* __restrict__ c, const float* __restrict__ probs2,
                      const float* __restrict__ v2, const bf16* __restrict__ v3,
                      float* __restrict__ out) {
  int idx = blockIdx.x * blockDim.y + threadIdx.y;
  if (idx >= NB * KK) return;
  int n = idx / KK, k = idx - n * KK;
  int lane = threadIdx.x;
  const float* ap = v2 + (size_t)idx * D_;
  const bf16* bp = v3 + (size_t)idx * D_;
  const float* u1p = u1 + n * D_;
  const float* u2p = u2 + n * D_;
  const float* cp = c + n * D_;
  float p2L = probs2[n * (LL + 1) + LL];
  float a1 = 0.f, a2 = 0.f;
  for (int d = lane; d < D_; d += 64) {
    a1 += u1p[d] * ap[d];
    a2 += (u2p[d] + p2L * cp[d]) * toF(bp[d]);
  }
#pragma unroll
  for (int off = 32; off; off >>= 1) { a1 += __shfl_down(a1, off); a2 += __shfl_down(a2, off); }
  if (lane == 0) {
    const float scale = 0.05773502691896258f;  // 1/sqrt(300)
    out[(size_t)n * 2 * KK + k] = a1 * scale;
    out[(size_t)n * 2 * KK + KK + k] = a2 * scale;
  }
}

extern "C" void kernel_launch(void* const* d_in, const int* in_sizes, int n_in,
                              void* d_out, int out_size, void* d_ws, size_t ws_size,
                              hipStream_t stream) {
  const float* t2    = (const float*)d_in[0];
  const float* v2    = (const float*)d_in[1];
  const float* score = (const float*)d_in[2];
  const int*   eidx  = (const int*)d_in[3];
  const void*  gmask = d_in[4];
  const void*  kpm   = d_in[5];
  const void*  npm   = d_in[6];
  const int*   iedge = (const int*)d_in[7];
  const float* txtW  = (const float*)d_in[8];
  const float* txtAs = (const float*)d_in[9];
  const float* txtAd = (const float*)d_in[10];
  const float* txtB  = (const float*)d_in[11];
  const float* imgW  = (const float*)d_in[12];
  const float* imgAs = (const float*)d_in[13];
  const float* imgAd = (const float*)d_in[14];
  const float* imgB  = (const float*)d_in[15];
  const float* w1    = (const float*)d_in[16];
  const float* b1    = (const float*)d_in[17];
  const float* w2    = (const float*)d_in[18];
  const float* b2    = (const float*)d_in[19];
  const float* lng   = (const float*)d_in[20];
  const float* lnb   = (const float*)d_in[21];
  float* out = (float*)d_out;

  char* ws = (char*)d_ws;
  size_t off = 0;
  auto alloc = [&](size_t bytes) -> char* {
    char* p = ws + off;
    off += (bytes + 511) & ~(size_t)511;
    return p;
  };
  int*   mmode = (int*)alloc(64);
  float* c    = (float*)alloc((size_t)NB * D_ * 4);
  float* u1   = (float*)alloc((size_t)NB * D_ * 4);
  float* u2   = (float*)alloc((size_t)NB * D_ * 4);
  float* lg1  = (float*)alloc((size_t)NB * LL * 4);
  float* lg2  = (float*)alloc((size_t)NB * (LL + 1) * 4);
  float* wsrc = (float*)alloc((size_t)H_ * D_ * 4);
  float* wdst = (float*)alloc((size_t)H_ * D_ * 4);
  float* asrc = (float*)alloc((size_t)NB * LL * H_ * 4);
  float* adst = (float*)alloc((size_t)NB * LL * H_ * 4);
  int* csrT   = (int*)alloc((size_t)NB * ETXT * 4);
  int* offT   = (int*)alloc((size_t)NB * (LL + 1) * 4);
  int* csrI   = (int*)alloc((size_t)EIMG * 4);
  int* offI   = (int*)alloc((size_t)(KK + 1) * 4);
  bf16* X   = (bf16*)alloc((size_t)NB * LL * D_ * 2);
  bf16* V   = (bf16*)alloc((size_t)NB * KK * D_ * 2);
  bf16* Bp2 = (bf16*)alloc((size_t)320 * KP2 * 2);
  size_t havail = (ws_size > off) ? (ws_size - off) : 0;
  bf16* agg = (bf16*)(ws + off);
  size_t per_g_txt = (size_t)LL * KP2 * 2;
  int cg = (int)(havail / per_g_txt);
  if (cg < 1) cg = 1;
  if (cg > NB) cg = NB;
  size_t per_g_img = (size_t)KK * KP2 * 2;
  int cgi = (int)(havail / per_g_img);
  if (cgi < 1) cgi = 1;
  if (cgi > NB) cgi = NB;

  dim3 b64x4(64, 4);

  k_detect<<<1, 256, 0, stream>>>((const unsigned int*)kpm, NB * LL / 4, mmode);
  k_zero<<<(NB * D_ + 255) / 256, 256, 0, stream>>>(c, u1, u2, NB * D_);
  k_csr<<<NB, 256, 0, stream>>>(eidx, 2 * ETXT, ETXT, LL, csrT, offT);
  k_csr<<<1, 256, 0, stream>>>(iedge, 0, EIMG, KK, csrI, offI);

  // phase 0: pa_token softmax probs; c + u1 partial sums
  k_logits_tok<<<(NB * LL + 3) / 4, b64x4, 0, stream>>>(t2, w1, b1, kpm, mmode, lg1, NB * LL);
  k_probs<<<NB, 256, 0, stream>>>(lg1, LL);
  k_cu1<<<dim3(NB, LL / 128), 128, 0, stream>>>(t2, score, lg1, c, u1);

  // text GAT (2 layers), chunked over graphs, in-place on X
  for (int layer = 0; layer < 2; ++layer) {
    const float* W = txtW + (size_t)layer * D_ * H_ * D_;
    k_packB2<<<(320 * KP2 + 255) / 256, 256, 0, stream>>>(W, Bp2);
    k_wvec<<<(2 * H_ * D_ + 255) / 256, 256, 0, stream>>>(
        W, txtAs + layer * H_ * D_, txtAd + layer * H_ * D_, wsrc, wdst);
    for (int g0 = 0; g0 < NB; g0 += cg) {
      int gs = (cg < NB - g0) ? cg : (NB - g0);
      int M = gs * LL;
      bf16* Xout = X + (size_t)g0 * LL * D_;
      if (layer == 0) {
        const float* Xin = t2 + (size_t)g0 * LL * D_;
        k_asrc<float><<<(M + 3) / 4, b64x4, 0, stream>>>(Xin, wsrc, wdst, asrc, adst, M);
        k_agg<float><<<M, 128, 0, stream>>>(Xin, asrc, adst, csrT, offT, ETXT, LL, g0, 1, agg);
      } else {
        const bf16* Xin = X + (size_t)g0 * LL * D_;
        k_asrc<bf16><<<(M + 3) / 4, b64x4, 0, stream>>>(Xin, wsrc, wdst, asrc, adst, M);
        k_agg<bf16><<<M, 128, 0, stream>>>(Xin, asrc, adst, csrT, offT, ETXT, LL, g0, 1, agg);
      }
      k_gemm_ln<<<(M + 63) / 64, 256, 0, stream>>>(
          agg, Bp2, txtB + layer * D_, lng, lnb, gmask, mmode, g0, LL, M, Xout);
    }
  }

  // image GAT (2 layers), shared edges, no gnn_mask, in-place on V
  for (int layer = 0; layer < 2; ++layer) {
    const float* W = imgW + (size_t)layer * D_ * H_ * D_;
    k_packB2<<<(320 * KP2 + 255) / 256, 256, 0, stream>>>(W, Bp2);
    k_wvec<<<(2 * H_ * D_ + 255) / 256, 256, 0, stream>>>(
        W, imgAs + layer * H_ * D_, imgAd + layer * H_ * D_, wsrc, wdst);
    for (int g0 = 0; g0 < NB; g0 += cgi) {
      int gs = (cgi < NB - g0) ? cgi : (NB - g0);
      int M = gs * KK;
      bf16* Vout = V + (size_t)g0 * KK * D_;
      if (layer == 0) {
        const float* Vin = v2 + (size_t)g0 * KK * D_;
        k_asrc<float><<<(M + 3) / 4, b64x4, 0, stream>>>(Vin, wsrc, wdst, asrc, adst, M);
        k_agg<float><<<M, 128, 0, stream>>>(Vin, asrc, adst, csrI, offI, EIMG, KK, 0, 0, agg);
      } else {
        const bf16* Vin = V + (size_t)g0 * KK * D_;
        k_asrc<bf16><<<(M + 3) / 4, b64x4, 0, stream>>>(Vin, wsrc, wdst, asrc, adst, M);
        k_agg<bf16><<<M, 128, 0, stream>>>(Vin, asrc, adst, csrI, offI, EIMG, KK, 0, 0, agg);
      }
      k_gemm_ln<<<(M + 63) / 64, 256, 0, stream>>>(
          agg, Bp2, imgB + layer * D_, lng, lnb, nullptr, mmode, 0, KK, M, Vout);
    }
  }

  // epilogue: pa_np probs -> u2 partial sums, then a1/a2
  k_logits_np<<<(NB * (LL + 1) + 3) / 4, b64x4, 0, stream>>>(X, c, w2, b2, npm, mmode, lg2);
  k_probs<<<NB, 256, 0, stream>>>(lg2, LL + 1);
  k_u2<<<dim3(NB, LL / 128), 128, 0, stream>>>(X, lg2, u2);
  k_out<<<(NB * KK + 3) / 4, b64x4, 0, stream>>>(u1, u2, c, lg2, v2, V, out);
}